// Round 14
// baseline (99.914 us; speedup 1.0000x reference)
//
#include <hip/hip_runtime.h>
#include <hip/hip_cooperative_groups.h>

// x (B=16, C=256, N=4096) fp32.
//   m[b,c]     = mean_n x[b,c,n]
//   score[b,n] = sum_c x[b,c,n] * m[b,c];  out = sigmoid(score)  (B,1,1,N)
//
// Primary: single-pass cooperative kernel — all of x (64 MiB) held in
// registers across grid.sync (512 blocks x 256 thr x 32 float4 = x).
// Fallback (if coop launch unavailable): proven 3-kernel two-pass path.

#define B_DIM 16
#define C_DIM 256
#define N_DIM 4096

namespace cg = cooperative_groups;

// ======================= cooperative fused path =======================
#define CSPLIT 8               // c-chunks of 32
#define CCHUNK 32              // c's per block
#define COOP_BLKS (B_DIM * CSPLIT * 4)  // 512

__global__ __launch_bounds__(256, 2) void fused_kernel(
    const float* __restrict__ x, float* __restrict__ msum,
    float* __restrict__ partials, float* __restrict__ out) {
  cg::grid_group grid = cg::this_grid();

  const int bid = blockIdx.x;
  const int nt = bid & 3;            // n-tile [nt*1024, +1024)
  const int cs = (bid >> 2) & 7;     // c-chunk [cs*32, +32)
  const int b = bid >> 5;
  const int t = threadIdx.x;
  const int n0 = nt * 1024 + t * 4;

  __shared__ float lds_sums[256][33];
  __shared__ float lds2[8][32];
  __shared__ float lds_m[32];

  // ---- Phase A: load x into regs, accumulate per-c n-partial sums ----
  const float* xb =
      x + (size_t)b * C_DIM * N_DIM + (size_t)(cs * CCHUNK) * N_DIM + n0;
  float4 v[CCHUNK];
#pragma unroll
  for (int c = 0; c < CCHUNK; ++c) {
    v[c] = *reinterpret_cast<const float4*>(xb + (size_t)c * N_DIM);
    lds_sums[t][c] = (v[c].x + v[c].y) + (v[c].z + v[c].w);
  }
  __syncthreads();
  {
    const int c = t & 31;
    const int chunk = t >> 5;
    float s = 0.0f;
#pragma unroll
    for (int r = 0; r < 32; ++r) s += lds_sums[chunk * 32 + r][c];
    lds2[chunk][c] = s;
  }
  __syncthreads();
  if (t < 32) {
    float s = 0.0f;
#pragma unroll
    for (int ch = 0; ch < 8; ++ch) s += lds2[ch][t];
    atomicAdd(&msum[b * C_DIM + cs * CCHUNK + t], s);
  }

  grid.sync();  // means complete, device-visible

  // ---- Phase B: dot register-held x with means ----
  if (t < 32) lds_m[t] = msum[b * C_DIM + cs * CCHUNK + t] * (1.0f / N_DIM);
  __syncthreads();
  float4 acc = make_float4(0.f, 0.f, 0.f, 0.f);
#pragma unroll
  for (int c = 0; c < CCHUNK; ++c) {
    const float w = lds_m[c];
    acc.x += v[c].x * w;
    acc.y += v[c].y * w;
    acc.z += v[c].z * w;
    acc.w += v[c].w * w;
  }
  *reinterpret_cast<float4*>(partials + ((size_t)cs * B_DIM + b) * N_DIM +
                             n0) = acc;

  grid.sync();  // partials complete

  // ---- Phase C: first 64 blocks reduce 8 partials + sigmoid ----
  if (bid < 64) {
    const int i4 = (bid * 256 + t) * 4;
    float4 s = make_float4(0.f, 0.f, 0.f, 0.f);
#pragma unroll
    for (int csr = 0; csr < CSPLIT; ++csr) {
      float4 p = *reinterpret_cast<const float4*>(
          partials + (size_t)csr * (B_DIM * N_DIM) + i4);
      s.x += p.x; s.y += p.y; s.z += p.z; s.w += p.w;
    }
    float4 o;
    o.x = 1.0f / (1.0f + __expf(-s.x));
    o.y = 1.0f / (1.0f + __expf(-s.y));
    o.z = 1.0f / (1.0f + __expf(-s.z));
    o.w = 1.0f / (1.0f + __expf(-s.w));
    *reinterpret_cast<float4*>(out + i4) = o;
  }
}

// ======================= fallback: proven R2 path =======================
#define FB_CSPLIT 16
#define FB_CCHUNK 16
#define FB_NTILE 1024

__global__ __launch_bounds__(256) void mean_rows_kernel(
    const float* __restrict__ x, float* __restrict__ m) {
  const int row = blockIdx.x;
  const float4* xr = reinterpret_cast<const float4*>(x + (size_t)row * N_DIM);
  float s = 0.0f;
#pragma unroll
  for (int i = 0; i < 4; ++i) {
    float4 v = xr[threadIdx.x + i * 256];
    s += (v.x + v.y) + (v.z + v.w);
  }
#pragma unroll
  for (int off = 32; off > 0; off >>= 1) s += __shfl_down(s, off, 64);
  __shared__ float wsum[4];
  const int lane = threadIdx.x & 63;
  const int wid = threadIdx.x >> 6;
  if (lane == 0) wsum[wid] = s;
  __syncthreads();
  if (threadIdx.x == 0) {
    float t = (wsum[0] + wsum[1]) + (wsum[2] + wsum[3]);
    m[row] = t * (1.0f / (float)N_DIM);
  }
}

__global__ __launch_bounds__(256) void partial_score_kernel(
    const float* __restrict__ x, const float* __restrict__ m,
    float* __restrict__ partials) {
  const int bid = blockIdx.x;
  const int cs = bid & (FB_CSPLIT - 1);
  const int nt = (bid >> 4) & 3;
  const int b = bid >> 6;

  __shared__ float ms[FB_CCHUNK];
  if (threadIdx.x < FB_CCHUNK)
    ms[threadIdx.x] = m[b * C_DIM + cs * FB_CCHUNK + threadIdx.x];
  __syncthreads();

  const int n0 = nt * FB_NTILE + threadIdx.x * 4;
  const float* xb =
      x + (size_t)b * C_DIM * N_DIM + (size_t)(cs * FB_CCHUNK) * N_DIM + n0;

  float4 acc = make_float4(0.f, 0.f, 0.f, 0.f);
#pragma unroll
  for (int c = 0; c < FB_CCHUNK; ++c) {
    float4 v = *reinterpret_cast<const float4*>(xb + (size_t)c * N_DIM);
    float w = ms[c];
    acc.x += v.x * w;
    acc.y += v.y * w;
    acc.z += v.z * w;
    acc.w += v.w * w;
  }
  float* p = partials + ((size_t)cs * B_DIM + b) * N_DIM + n0;
  *reinterpret_cast<float4*>(p) = acc;
}

__global__ __launch_bounds__(256) void reduce_sigmoid_kernel(
    const float* __restrict__ partials, float* __restrict__ out) {
  const int i4 = (blockIdx.x * 256 + threadIdx.x) * 4;
  float4 s = make_float4(0.f, 0.f, 0.f, 0.f);
#pragma unroll
  for (int cs = 0; cs < FB_CSPLIT; ++cs) {
    float4 v = *reinterpret_cast<const float4*>(
        partials + (size_t)cs * (B_DIM * N_DIM) + i4);
    s.x += v.x; s.y += v.y; s.z += v.z; s.w += v.w;
  }
  float4 o;
  o.x = 1.0f / (1.0f + __expf(-s.x));
  o.y = 1.0f / (1.0f + __expf(-s.y));
  o.z = 1.0f / (1.0f + __expf(-s.z));
  o.w = 1.0f / (1.0f + __expf(-s.w));
  *reinterpret_cast<float4*>(out + i4) = o;
}

extern "C" void kernel_launch(void* const* d_in, const int* in_sizes, int n_in,
                              void* d_out, int out_size, void* d_ws,
                              size_t ws_size, hipStream_t stream) {
  const float* x = (const float*)d_in[0];
  float* out = (float*)d_out;
  float* msum = (float*)d_ws;                      // 16 KiB
  float* partials = (float*)d_ws + B_DIM * C_DIM;  // up to 4 MiB

  // Host-side capability check (no stream ops; capture-safe, deterministic).
  int coop = 0;
  (void)hipDeviceGetAttribute(&coop, hipDeviceAttributeCooperativeLaunch, 0);
  int max_blk_per_cu = 0;
  (void)hipOccupancyMaxActiveBlocksPerMultiprocessor(
      &max_blk_per_cu, reinterpret_cast<const void*>(fused_kernel), 256, 0);
  int num_cu = 0;
  (void)hipDeviceGetAttribute(&num_cu,
                              hipDeviceAttributeMultiprocessorCount, 0);

  bool use_coop = (coop != 0) && (max_blk_per_cu * num_cu >= COOP_BLKS);

  if (use_coop) {
    hipMemsetAsync(msum, 0, B_DIM * C_DIM * sizeof(float), stream);
    void* args[] = {(void*)&x, (void*)&msum, (void*)&partials, (void*)&out};
    hipError_t e = hipLaunchCooperativeKernel(
        reinterpret_cast<void*>(fused_kernel), dim3(COOP_BLKS), dim3(256),
        args, 0, stream);
    if (e == hipSuccess) return;
    // fall through to the proven path if the launch was rejected
  }

  mean_rows_kernel<<<B_DIM * C_DIM, 256, 0, stream>>>(x, msum);
  partial_score_kernel<<<B_DIM * 4 * FB_CSPLIT, 256, 0, stream>>>(x, msum,
                                                                  partials);
  reduce_sigmoid_kernel<<<(B_DIM * N_DIM) / 1024, 256, 0, stream>>>(partials,
                                                                    out);
}